// Round 6
// baseline (162.545 us; speedup 1.0000x reference)
//
#include <hip/hip_runtime.h>

#define NGRAPH 4096
#define NNODE  64
#define NDIM   128
#define NLAYER 3
#define PH 136   // sh pitch (bf16): 68 dwords === 4 mod 32 -> bank-uniform b128 row reads
#define PZ 72    // zt pitch (bf16): 36 dwords === 4 mod 32 (proven family, R8's PA)

typedef __attribute__((ext_vector_type(8))) short short8;
typedef __attribute__((ext_vector_type(4))) float f32x4;
typedef __bf16 bf16x2 __attribute__((ext_vector_type(2)));

static __device__ inline ushort f2bf(float f) {  // RNE fp32 -> bf16 (fallback path)
  unsigned u = __float_as_uint(f);
  u += 0x7FFF + ((u >> 16) & 1);
  return (ushort)(u >> 16);
}

// packed fp32x2 -> bf16x2 in one HW instr on gfx950 (v_cvt_pk_bf16_f32)
static __device__ inline unsigned pkbf(float x, float y) {
#if __has_builtin(__builtin_amdgcn_cvt_pk_bf16_f32)
  bf16x2 v = __builtin_amdgcn_cvt_pk_bf16_f32(x, y);
  return __builtin_bit_cast(unsigned, v);
#else
  return (unsigned)f2bf(x) | ((unsigned)f2bf(y) << 16);
#endif
}

// W in bf16, native [l][k_out][d] layout (B-frag reads W rows directly).
__device__ __align__(16) ushort g_wbf[NLAYER * NDIM * NDIM];

__global__ __launch_bounds__(256) void convert_w(const float* __restrict__ W) {
  int i = blockIdx.x * 256 + threadIdx.x;   // 192 blocks, exact
  g_wbf[i] = f2bf(W[i]);
}

// R14 = R13 + the z-transpose moved from ds_bpermute to a WAVE-PRIVATE zT LDS
// round-trip.  R13 post-mortem: bpermutes were the largest remaining LDS
// consumer (128 instr/block-layer + most of the 7.9e6 conflict cycles).  Key
// fact: in this wave shape, m2's d-region == m1's kout-region, so each wave
// consumes only z it produced itself -> the transpose needs NO barrier and no
// cross-wave exchange.  zT round-trip = 32 ds_write_b64 + 16 ds_read_b128 per
// block-layer (2.7x fewer LDS instr than bpermute) with 2-way-max (free) bank
// patterns.  Also deletes 32 cndmask/wave-layer and the 16-VGPR zc file.
// Everything else byte-identical to R13 (barriers, staging, fbr hoist, W).
// LDS 53.2 KB -> 3 blocks/CU (= R13's measured residency anyway).
__global__ __launch_bounds__(256, 4) void mpnn_mfma(
    const int* __restrict__ fps, const float* __restrict__ adj,
    const float* __restrict__ emb, const float* __restrict__ bias,
    float* __restrict__ out) {
  __shared__ __align__(16) ushort sh0[NNODE * PH];    // h ping  17408 B
  __shared__ __align__(16) ushort sh1[NNODE * PH];    // adj stage -> h pong  17408 B
  __shared__ __align__(16) ushort zt[4 * 32 * PZ];    // wave-private zT slabs 18432 B

  const int g    = blockIdx.x;
  const int t    = threadIdx.x;
  const int w    = t >> 6;        // wave 0..3
  const int lane = t & 63;
  const int r    = lane & 15;     // MFMA row/col index
  const int q    = lane >> 4;     // quad 0..3
  const int n0   = w << 5;        // wave's 32-wide kout region (m1) == d region (m2)

  // ---- gather h0 = bf16(emb[fps]) into sh0 ----
  const int* fg = fps + g * NNODE;
#pragma unroll
  for (int it = 0; it < 8; ++it) {
    int idx = it * 256 + t;               // 2048 float4s
    int n = idx >> 5;
    int c = (idx & 31) << 2;
    float4 v = *(const float4*)(emb + fg[n] * NDIM + c);
    uint2 u = {pkbf(v.x, v.y), pkbf(v.z, v.w)};
    *(uint2*)(sh0 + n * PH + c) = u;
  }

  // ---- adjacency -> sh1: bf16(I + A), staged once, cooperatively coalesced ----
  const float* adjg = adj + (size_t)g * NNODE * NNODE;
#pragma unroll
  for (int it = 0; it < 4; ++it) {
    int idx = it * 256 + t;               // 1024 float4s
    int n = idx >> 4;
    int c = (idx & 15) << 2;
    float4 v = *(const float4*)(adjg + n * NNODE + c);
    v.x += (n == c + 0) ? 1.0f : 0.0f;    // fold residual: I + A
    v.y += (n == c + 1) ? 1.0f : 0.0f;
    v.z += (n == c + 2) ? 1.0f : 0.0f;
    v.w += (n == c + 3) ? 1.0f : 0.0f;
    uint2 u = {pkbf(v.x, v.y), pkbf(v.z, v.w)};
    *(uint2*)(sh1 + n * PH + c) = u;
  }

  // ---- bias for all layers, both slabs -> registers ----
  float bv[NLAYER][2];
#pragma unroll
  for (int l = 0; l < NLAYER; ++l) {
    bv[l][0] = bias[l * NDIM + n0 + r];
    bv[l][1] = bias[l * NDIM + n0 + 16 + r];
  }

  __syncthreads();

  // ---- (I+A) B-frags -> registers, once per block (layer-invariant) ----
  // fbr[kh][nt] lane(r,q): (I+A)[node'=nt*16+r][node=kh*32+8q+e]
  short8 fbr[2][4];
#pragma unroll
  for (int kh = 0; kh < 2; ++kh)
#pragma unroll
    for (int nt = 0; nt < 4; ++nt)
      fbr[kh][nt] = *(const short8*)(sh1 + (nt * 16 + r) * PH + kh * 32 + 8 * q);
  __syncthreads();   // all fbr reads done before layer-0 m2 writes recycle sh1

  // wave-private zT slab base (row = kout_local, col = node)
  ushort* ztw = zt + w * 32 * PZ;

#pragma unroll 1   // real loop: avoid cross-layer load hoisting -> spill (R6 lesson)
  for (int l = 0; l < NLAYER; ++l) {
    const ushort* shr = (l & 1) ? sh1 : sh0;   // read buffer
    ushort*       shw = (l & 1) ? sh0 : sh1;   // write buffer (ping-pong)
    const ushort* Wl  = g_wbf + l * NDIM * NDIM;

    // ---- m1: z[node][n0-region(32)] = relu(h * W^T + b), two 16-slabs ----
    f32x4 acc[2][4];
#pragma unroll
    for (int s = 0; s < 2; ++s)
#pragma unroll
      for (int mt = 0; mt < 4; ++mt)
        acc[s][mt] = (f32x4){bv[l][s], bv[l][s], bv[l][s], bv[l][s]};
#pragma unroll
    for (int k0 = 0; k0 < NDIM; k0 += 32) {
      short8 ah[4];                       // loaded ONCE, feeds both slabs
#pragma unroll
      for (int mt = 0; mt < 4; ++mt)
        ah[mt] = *(const short8*)(shr + (mt * 16 + r) * PH + k0 + 8 * q);
#pragma unroll
      for (int s = 0; s < 2; ++s) {
        short8 bw = *(const short8*)(Wl + (n0 + s * 16 + r) * NDIM + k0 + 8 * q);
#pragma unroll
        for (int mt = 0; mt < 4; ++mt)
          acc[s][mt] = __builtin_amdgcn_mfma_f32_16x16x32_bf16(ah[mt], bw, acc[s][mt], 0, 0, 0);
      }
    }

    // ---- relu -> zT[kout_local][node] in the wave's private slab ----
    // C-frag lane(r,q) reg j = z[node=mt*16+4q+j][kout=n0+s*16+r]
    // -> write uint2 at zT row (s*16+r), cols mt*16+4q..+3  (8 b64/wave-layer)
#pragma unroll
    for (int s = 0; s < 2; ++s)
#pragma unroll
      for (int mt = 0; mt < 4; ++mt) {
        f32x4 a = acc[s][mt];
        uint2 u = {pkbf(fmaxf(a[0], 0.f), fmaxf(a[1], 0.f)),
                   pkbf(fmaxf(a[2], 0.f), fmaxf(a[3], 0.f))};
        *(uint2*)(ztw + (s * 16 + r) * PZ + mt * 16 + 4 * q) = u;
      }

    // ---- m2: houtT[d in n0-region][node'] = zT * (I+A)^T ----
    // az lane(r,q): z[node=kh*32+8q+e][d=n0+s*16+r] = one contiguous b128 from
    // zT row (s*16+r).  Same-wave DS ordering: no barrier needed.
    f32x4 acc2[2][4];
#pragma unroll
    for (int s = 0; s < 2; ++s)
#pragma unroll
      for (int nt = 0; nt < 4; ++nt) acc2[s][nt] = (f32x4){0.f, 0.f, 0.f, 0.f};
#pragma unroll
    for (int s = 0; s < 2; ++s) {
#pragma unroll
      for (int kh = 0; kh < 2; ++kh) {
        short8 az = *(const short8*)(ztw + (s * 16 + r) * PZ + kh * 32 + 8 * q);
#pragma unroll
        for (int nt = 0; nt < 4; ++nt)
          acc2[s][nt] = __builtin_amdgcn_mfma_f32_16x16x32_bf16(az, fbr[kh][nt], acc2[s][nt], 0, 0, 0);
      }
    }

    if (l < NLAYER - 1) {
      // write h into the OTHER buffer: no pre-barrier needed
#pragma unroll
      for (int s = 0; s < 2; ++s)
#pragma unroll
        for (int nt = 0; nt < 4; ++nt) {
          f32x4 a = acc2[s][nt];
          uint2 u = {pkbf(a[0], a[1]), pkbf(a[2], a[3])};
          *(uint2*)(shw + (nt * 16 + r) * PH + n0 + s * 16 + 4 * q) = u;
        }
      __syncthreads();   // single barrier per layer
    } else {
      // ---- sum-pool: out[g][d] = sum_node' h[node'][d] ----
#pragma unroll
      for (int s = 0; s < 2; ++s) {
        f32x4 sum;
#pragma unroll
        for (int i = 0; i < 4; ++i)
          sum[i] = acc2[s][0][i] + acc2[s][1][i] + acc2[s][2][i] + acc2[s][3][i];
#pragma unroll
        for (int m = 1; m <= 8; m <<= 1) {
          sum[0] += __shfl_xor(sum[0], m);
          sum[1] += __shfl_xor(sum[1], m);
          sum[2] += __shfl_xor(sum[2], m);
          sum[3] += __shfl_xor(sum[3], m);
        }
        if (r == 0) {
          float4 o = {sum[0], sum[1], sum[2], sum[3]};
          *(float4*)(out + (size_t)g * NDIM + n0 + s * 16 + 4 * q) = o;
        }
      }
    }
  }
}

extern "C" void kernel_launch(void* const* d_in, const int* in_sizes, int n_in,
                              void* d_out, int out_size, void* d_ws, size_t ws_size,
                              hipStream_t stream) {
  const int*   fps  = (const int*)d_in[0];
  const float* adj  = (const float*)d_in[1];
  const float* emb  = (const float*)d_in[2];
  const float* W    = (const float*)d_in[3];
  const float* bias = (const float*)d_in[4];
  float* out = (float*)d_out;

  hipLaunchKernelGGL(convert_w, dim3(192), dim3(256), 0, stream, W);
  hipLaunchKernelGGL(mpnn_mfma, dim3(NGRAPH), dim3(256), 0, stream,
                     fps, adj, emb, bias, out);
}